// Round 4
// baseline (10628.279 us; speedup 1.0000x reference)
//
#include <hip/hip_runtime.h>
#include <hip/hip_bf16.h>

// Particle-filter VAE ELBO, MI355X single-fused-kernel implementation.
// Round 4: 1024 threads (16 waves, 4/SIMD); phase C = per-wave-16-particles
// with shfl-assembled GEMM2 B-operand (no LDS transpose stage -> kills the
// 1.57e8 bank conflicts); phase E (obs ll) MFMA-ized in bf16. eps/RNG
// bit-identical to round 3.

#define WS_KG    0
#define WS_OMA   4096
#define WS_L     4608
#define WS_RSTDZ 5120
#define WS_RSTDX 5152
#define WS_CONST 5280

#define LOG2PI_F 1.8378770664093453f

typedef __attribute__((ext_vector_type(8))) short short8v;
typedef __attribute__((ext_vector_type(4))) float float4v;
typedef __attribute__((ext_vector_type(4))) unsigned uint4v;

#define MFMA_BF16(a, b, c) __builtin_amdgcn_mfma_f32_16x16x32_bf16((a), (b), (c), 0, 0, 0)

__device__ __forceinline__ unsigned rotl32(unsigned v, int r) {
  return (v << r) | (v >> (32 - r));
}

// Threefry-2x32, 20 rounds, exactly JAX's schedule.
__device__ __forceinline__ void tf2x32(unsigned k0, unsigned k1,
                                       unsigned c0, unsigned c1,
                                       unsigned& o0, unsigned& o1) {
  unsigned ks2 = k0 ^ k1 ^ 0x1BD11BDAu;
  unsigned x0 = c0 + k0, x1 = c1 + k1;
#define TF_R4(ra, rb, rc, rd) \
  x0 += x1; x1 = rotl32(x1, ra); x1 ^= x0; \
  x0 += x1; x1 = rotl32(x1, rb); x1 ^= x0; \
  x0 += x1; x1 = rotl32(x1, rc); x1 ^= x0; \
  x0 += x1; x1 = rotl32(x1, rd); x1 ^= x0;
  TF_R4(13, 15, 26, 6)  x0 += k1;  x1 += ks2 + 1u;
  TF_R4(17, 29, 16, 24) x0 += ks2; x1 += k0 + 2u;
  TF_R4(13, 15, 26, 6)  x0 += k0;  x1 += k1 + 3u;
  TF_R4(17, 29, 16, 24) x0 += k1;  x1 += ks2 + 4u;
  TF_R4(13, 15, 26, 6)  x0 += ks2; x1 += k0 + 5u;
#undef TF_R4
  o0 = x0; o1 = x1;
}

// XLA ErfInv32 polynomial (Giles).
__device__ __forceinline__ float erfinv_f(float x) {
  float w = -log1pf(-x * x);
  float p;
  if (w < 5.0f) {
    w -= 2.5f;
    p = 2.81022636e-08f;
    p = fmaf(p, w, 3.43273939e-07f);
    p = fmaf(p, w, -3.5233877e-06f);
    p = fmaf(p, w, -4.39150654e-06f);
    p = fmaf(p, w, 0.00021858087f);
    p = fmaf(p, w, -0.00125372503f);
    p = fmaf(p, w, -0.00417768164f);
    p = fmaf(p, w, 0.246640727f);
    p = fmaf(p, w, 1.50140941f);
  } else {
    w = sqrtf(w) - 3.0f;
    p = -0.000200214257f;
    p = fmaf(p, w, 0.000100950558f);
    p = fmaf(p, w, 0.00134934322f);
    p = fmaf(p, w, -0.00367342844f);
    p = fmaf(p, w, 0.00573950773f);
    p = fmaf(p, w, -0.0076224613f);
    p = fmaf(p, w, 0.00943887047f);
    p = fmaf(p, w, 1.00167406f);
    p = fmaf(p, w, 2.83297682f);
  }
  return p * x;
}

__device__ __forceinline__ float normal_from_bits(unsigned bits) {
  float f = __uint_as_float((bits >> 9) | 0x3f800000u) - 1.0f;  // [0,1)
  const float lo = -0.99999994f;
  float uu = fmaxf(lo, fmaf(f, 2.0f, lo));
  return 1.41421354f * erfinv_f(uu);
}

__device__ __forceinline__ float tanh_fast(float x) {
  float e = __expf(2.0f * x);
  return 1.0f - 2.0f * __builtin_amdgcn_rcpf(e + 1.0f);
}

// f32 -> bf16 bits, round-to-nearest-even.
__device__ __forceinline__ short f2bf(float f) {
  unsigned u = __float_as_uint(f);
  unsigned r = (u + 0x7fffu + ((u >> 16) & 1u)) >> 16;
  return (short)r;
}

__device__ __forceinline__ unsigned packbf(float a, float b) {
  return (unsigned)(unsigned short)f2bf(a) |
         ((unsigned)(unsigned short)f2bf(b) << 16);
}

// ---------------- precompute kernel: Kalman quantities into ws --------------
__global__ void precomp_kernel(const float* __restrict__ Rz,
                               const float* __restrict__ Rz0,
                               const float* __restrict__ Rx,
                               const float* __restrict__ Bobs,
                               float* __restrict__ ws) {
  __shared__ float svarx[128];
  __shared__ float svarz[16];
  __shared__ float sprec[16][16];
  __shared__ float saug[16][32];
  __shared__ float svq[16][16];
  __shared__ float sLm[16][16];
  __shared__ float skg[16][128];
  const int tid = threadIdx.x;  // 256 threads

  if (tid < 128) {
    float r = Rx[tid];
    svarx[tid] = fmaxf(r * r, 1e-8f);
    ws[WS_RSTDX + tid] = 1.0f / fmaxf(fabsf(r), 1e-4f);
  }
  if (tid == 0) {
    float a = 0.0f;
    for (int xx = 0; xx < 128; ++xx) a += logf(fmaxf(fabsf(Rx[xx]), 1e-4f));
    ws[WS_CONST + 0] = -a - 0.5f * 128.0f * LOG2PI_F;
  }
  __syncthreads();

  for (int set = 0; set < 2; ++set) {
    const float* Rzp = (set == 0) ? Rz0 : Rz;
    if (tid < 16) {
      float v = Rzp[tid] * Rzp[tid] + 1e-8f;
      svarz[tid] = v;
      ws[WS_RSTDZ + set * 16 + tid] = 1.0f / sqrtf(v);
    }
    __syncthreads();
    {
      int z1 = tid >> 4, z2 = tid & 15;
      float a = 0.0f;
      for (int xx = 0; xx < 128; ++xx)
        a += Bobs[z1 * 128 + xx] * Bobs[z2 * 128 + xx] / svarx[xx];
      if (z1 == z2) a += 1.0f / svarz[z1];
      sprec[z1][z2] = a;
    }
    __syncthreads();
    if (tid == 0) {
      for (int r = 0; r < 16; ++r)
        for (int c2 = 0; c2 < 32; ++c2)
          saug[r][c2] = (c2 < 16) ? sprec[r][c2] : ((c2 - 16 == r) ? 1.0f : 0.0f);
      for (int p = 0; p < 16; ++p) {
        float ip = 1.0f / saug[p][p];
        for (int c2 = 0; c2 < 32; ++c2) saug[p][c2] *= ip;
        for (int r = 0; r < 16; ++r) if (r != p) {
          float f = saug[r][p];
          for (int c2 = 0; c2 < 32; ++c2) saug[r][c2] -= f * saug[p][c2];
        }
      }
      for (int r = 0; r < 16; ++r)
        for (int c2 = 0; c2 < 16; ++c2)
          svq[r][c2] = 0.5f * (saug[r][16 + c2] + saug[c2][16 + r]) +
                       ((r == c2) ? 1e-8f : 0.0f);
      for (int j = 0; j < 16; ++j) {
        float d = svq[j][j];
        for (int s = 0; s < j; ++s) d -= sLm[j][s] * sLm[j][s];
        float dj = sqrtf(d);
        sLm[j][j] = dj;
        for (int r = j + 1; r < 16; ++r) {
          float a = svq[r][j];
          for (int s = 0; s < j; ++s) a -= sLm[r][s] * sLm[j][s];
          sLm[r][j] = a / dj;
        }
        for (int r = 0; r < j; ++r) sLm[r][j] = 0.0f;
      }
      float cc = 0.0f;
      for (int j = 0; j < 16; ++j) cc += logf(sLm[j][j]) - logf(sqrtf(svarz[j]));
      ws[WS_CONST + 1 + set] = cc;
      for (int r = 0; r < 16; ++r)
        for (int c2 = 0; c2 < 16; ++c2)
          ws[WS_L + set * 256 + r * 16 + c2] = sLm[r][c2];
    }
    __syncthreads();
    for (int o = tid; o < 2048; o += 256) {
      int z = o >> 7, xx = o & 127;
      float a = 0.0f;
      for (int s = 0; s < 16; ++s) a += saug[z][16 + s] * Bobs[s * 128 + xx];
      a /= svarx[xx];
      skg[z][xx] = a;
      ws[WS_KG + set * 2048 + o] = a;
    }
    __syncthreads();
    {
      int z = tid >> 4, s = tid & 15;
      float a = 0.0f;
      for (int xx = 0; xx < 128; ++xx) a += skg[z][xx] * Bobs[s * 128 + xx];
      ws[WS_OMA + set * 256 + tid] = ((z == s) ? 1.0f : 0.0f) - a;
    }
    __syncthreads();
  }
}

// ---------------- main particle-filter kernel: 1 block = 1 batch -----------
__global__ __launch_bounds__(1024) void pf_kernel(
    const float* __restrict__ xg, const float* __restrict__ ug,
    const float* __restrict__ Bobs, const float* __restrict__ Obias,
    const float* __restrict__ mg, const float* __restrict__ ng,
    const float* __restrict__ Wug, const float* __restrict__ hg,
    const float* __restrict__ W0g, const float* __restrict__ b0g,
    const float* __restrict__ ws, float* __restrict__ out) {
  __shared__ short8v sNF[32][32];      // n A1-frags (K=z padded 32, q<2 only)
  __shared__ short8v sMF[32][32];      // m^T A2-frags
  __shared__ short8v sBF[8][32];       // B_obs^T E-A-frags
  __shared__ float sQz0[16][128];      // carry Qz (f32)
  __shared__ float sQz1[16][128];      // resampled Qz (f32)
  __shared__ float sPM[16][128];       // prior mean
  __shared__ float sPMp[8][16][17];    // GEMM2 N-half partials
  __shared__ __align__(16) short sQnT[128][40];  // Qz_new bf16 [p][z], 80B rows
  __shared__ __align__(16) short sZbT[128][40];  // resampled bf16 [p][z]
  __shared__ float sEps[16][128];
  __shared__ float sWV[512];           // Wu@v + h
  __shared__ float sXT[128];           // x_t - Obs_bias
  __shared__ float sXR[128];           // sXT * sRX
  __shared__ float sRX[128];           // 1/std_x
  __shared__ float sKx[16];
  __shared__ float sCW[128];
  __shared__ int   sIDX[128];
  __shared__ float sLLC[8][128];       // proposal/prior partials
  __shared__ float sLLE[2][128];       // obs quad partials (x-halves)
  __shared__ float sOMA1[16][16];
  __shared__ float sL1[16][16];
  __shared__ float sRSZ1[16];
  __shared__ unsigned sK2b[2];

  const int tid  = threadIdx.x;
  const int b    = blockIdx.x;
  const int lane = tid & 63;
  const int wid  = tid >> 6;       // 0..15
  const int q    = lane >> 4;      // 0..3
  const int r16  = lane & 15;

  const short8v zero8 = {0, 0, 0, 0, 0, 0, 0, 0};
  const float4v zero4 = {0.f, 0.f, 0.f, 0.f};

  // ---------------- init staging ----------------
  {
    int kt = tid >> 5, sl = tid & 31, qq = sl >> 4, rr = sl & 15;
    short8v vn, vm;
#pragma unroll
    for (int i = 0; i < 8; ++i) {
      vn[i] = f2bf(ng[(size_t)(kt * 16 + rr) * 16 + qq * 8 + i]);
      vm[i] = f2bf(mg[(size_t)(kt * 16 + qq * 8 + i) * 16 + rr]);
    }
    sNF[kt][sl] = vn;
    sMF[kt][sl] = vm;
  }
  if (tid < 256) {
    int xt = tid >> 5, sl = tid & 31, qq = sl >> 4, rr = sl & 15;
    short8v v;
#pragma unroll
    for (int i = 0; i < 8; ++i)
      v[i] = f2bf(Bobs[(size_t)(qq * 8 + i) * 128 + xt * 16 + rr]);
    sBF[xt][sl] = v;
  }
  if (tid < 128) sRX[tid] = ws[WS_RSTDX + tid];
  if (tid < 256) {
    int z = tid >> 4, s = tid & 15;
    sOMA1[z][s] = ws[WS_OMA + 256 + tid];
    sL1[z][s]   = ws[WS_L + 256 + tid];
  }
  if (tid < 16) sRSZ1[tid] = ws[WS_RSTDZ + 16 + tid];
  if (tid == 0) {
    unsigned kt0, kt1;
    tf2x32(0u, 42u, 0u, 0u, kt0, kt1);
    sK2b[0] = kt0; sK2b[1] = kt1;
  }
  const float cobs = ws[WS_CONST + 0];
  const float cc0  = ws[WS_CONST + 1];
  const float cc1  = ws[WS_CONST + 2];
  __syncthreads();

  float elbo = 0.0f;
  unsigned* qn32 = (unsigned*)&sQnT[0][0];   // row stride 20 u32
  unsigned* zb32 = (unsigned*)&sZbT[0][0];

  for (int t = 0; t < 512; ++t) {
    // ===== phase A: gather | bf16-copy | x-stage | wv ; RNG on all =========
    if (t > 0) {
      if (wid < 8) {
#pragma unroll
        for (int c = 0; c < 4; ++c) {
          int f = tid + 512 * c;
          int z = f >> 7, kk = f & 127;
          sQz1[z][kk] = sQz0[z][sIDX[kk]];
        }
      } else if (wid < 12) {
        int base = tid - 512;  // 0..255
#pragma unroll
        for (int c = 0; c < 4; ++c) {
          int j = base + 256 * c;
          int row = j >> 3, w = j & 7;
          zb32[row * 20 + w] = qn32[sIDX[row] * 20 + w];
        }
      } else if (wid == 12) {
#pragma unroll
        for (int h2 = 0; h2 < 2; ++h2) {
          int xx = lane + 64 * h2;
          float xv = xg[((size_t)b * 128 + xx) * 512 + t] - Obias[xx];
          sXT[xx] = xv;
          sXR[xx] = xv * sRX[xx];
        }
        int z = lane >> 2, xq = lane & 3;
        const float* Kgp = ws + WS_KG + 2048 + z * 128;
        float a = 0.0f;
        for (int jj = 0; jj < 32; ++jj) {
          int xx = xq + 4 * jj;
          a = fmaf(Kgp[xx], sXT[xx], a);
        }
        a += __shfl_xor(a, 1, 64);
        a += __shfl_xor(a, 2, 64);
        if (xq == 0) sKx[z] = a;
      } else if (wid == 13) {
        float v[8];
#pragma unroll
        for (int d = 0; d < 8; ++d) v[d] = ug[((size_t)b * 8 + d) * 512 + (t - 1)];
#pragma unroll
        for (int qq = 0; qq < 8; ++qq) {
          int N = lane + 64 * qq;
          const float4* wr = (const float4*)&Wug[N * 8];
          float4 wa = wr[0], wb = wr[1];
          float a = hg[N];
          a = fmaf(wa.x, v[0], a); a = fmaf(wa.y, v[1], a);
          a = fmaf(wa.z, v[2], a); a = fmaf(wa.w, v[3], a);
          a = fmaf(wb.x, v[4], a); a = fmaf(wb.y, v[5], a);
          a = fmaf(wb.z, v[6], a); a = fmaf(wb.w, v[7], a);
          sWV[N] = a;
        }
      }
    } else {
      if (wid == 12) {
#pragma unroll
        for (int h2 = 0; h2 < 2; ++h2) {
          int xx = lane + 64 * h2;
          float xv = xg[((size_t)b * 128 + xx) * 512] - Obias[xx];
          sXT[xx] = xv;
          sXR[xx] = xv * sRX[xx];
        }
      }
    }
    {  // RNG: 2 eps/thread, same counter mapping as round 3
      unsigned k2a = sK2b[0], k2b = sK2b[1];
#pragma unroll
      for (int j = 0; j < 2; ++j) {
        int f = tid + 1024 * j;
        unsigned o0, o1;
        tf2x32(k2a, k2b, 0u, (unsigned)(b * 2048 + f), o0, o1);
        sEps[f >> 7][f & 127] = normal_from_bits(o0 ^ o1);
      }
    }
    __syncthreads();

    // ===== phase C: transition, per-wave 16 particles, N-halves ============
    if (t > 0) {
      const int nh = wid >> 3, wp = wid & 7, p0 = wp * 16;
      short8v b1 = zero8;
      if (q < 2) b1 = *(const short8v*)&sZbT[p0 + r16][q * 8];
      const int sl = q * 16 + r16;          // valid for q<2
      const int srcA = 32 * q + r16;        // shfl sources (dest q = qd)
      const int srcB = srcA + 16;
      float4v acc = zero4;
#pragma unroll
      for (int kt2 = 0; kt2 < 16; ++kt2) {
        const int kt = nh * 16 + kt2;
        short8v a1 = zero8, a2 = zero8;
        if (q < 2) { a1 = sNF[kt][sl]; a2 = sMF[kt][sl]; }
        float4v cin = *(const float4v*)&sWV[kt * 16 + q * 4];
        float4v d1 = MFMA_BF16(a1, b1, cin);
        unsigned pk0 = packbf(tanh_fast(d1.x), tanh_fast(d1.y));
        unsigned pk1 = packbf(tanh_fast(d1.z), tanh_fast(d1.w));
        unsigned u0 = (unsigned)__shfl((int)pk0, srcA, 64);
        unsigned u1 = (unsigned)__shfl((int)pk1, srcA, 64);
        unsigned u2 = (unsigned)__shfl((int)pk0, srcB, 64);
        unsigned u3 = (unsigned)__shfl((int)pk1, srcB, 64);
        short8v b2 = zero8;
        if (q < 2) {
          uint4v uu = {u0, u1, u2, u3};
          b2 = __builtin_bit_cast(short8v, uu);
        }
        acc = MFMA_BF16(a2, b2, acc);
      }
      if (nh == 1) {
        sPMp[wp][4 * q + 0][r16] = acc.x;
        sPMp[wp][4 * q + 1][r16] = acc.y;
        sPMp[wp][4 * q + 2][r16] = acc.z;
        sPMp[wp][4 * q + 3][r16] = acc.w;
      }
      __syncthreads();
      if (nh == 0) {
        const int p = p0 + r16;
#pragma unroll
        for (int i = 0; i < 4; ++i) {
          int z = 4 * q + i;
          float tot = ((i == 0) ? acc.x : (i == 1) ? acc.y : (i == 2) ? acc.z : acc.w)
                      + sPMp[wp][z][r16];
          float zq = sQz1[z][p];
          sPM[z][p] = fmaf(0.1f, tot, 0.9f * zq);
        }
      }
      __syncthreads();
    }

    // ===== phase D: proposal sample + ll_pz/ll_qz ==========================
    {
      const int kk = tid & 127, zg = tid >> 7;  // zg 0..7, 2 z's each
      float ep[16];
#pragma unroll
      for (int s = 0; s < 16; ++s) ep[s] = sEps[s][kk];
      float part = 0.0f;
      if (zg == 0) {
        float qd = 0.0f;
#pragma unroll
        for (int s = 0; s < 16; ++s) qd = fmaf(ep[s], ep[s], qd);
        part = 0.5f * qd;
      }
      float qnv[2];
      if (t == 0) {
        float v0[8];
#pragma unroll
        for (int d = 0; d < 8; ++d) v0[d] = ug[((size_t)b * 8 + d) * 512];
        float pm0[16];
#pragma unroll
        for (int s = 0; s < 16; ++s) {
          float a = b0g[s];
#pragma unroll
          for (int d = 0; d < 8; ++d) a = fmaf(W0g[s * 8 + d], v0[d], a);
          pm0[s] = a;
        }
        const float* Kg0p = ws + WS_KG;
        const float* omap = ws + WS_OMA;
        const float* Lp   = ws + WS_L;
        const float* rsz  = ws + WS_RSTDZ;
#pragma unroll
        for (int zi = 0; zi < 2; ++zi) {
          int z = zg * 2 + zi;
          float mq = 0.0f;
          for (int xx = 0; xx < 128; ++xx)
            mq = fmaf(Kg0p[z * 128 + xx], sXT[xx], mq);
#pragma unroll
          for (int s = 0; s < 16; ++s) mq = fmaf(omap[z * 16 + s], pm0[s], mq);
          float qn = mq;
#pragma unroll
          for (int s = 0; s < 16; ++s) qn = fmaf(Lp[z * 16 + s], ep[s], qn);
          sQz0[z][kk] = qn;
          qnv[zi] = qn;
          float pz = b0g[z];
#pragma unroll
          for (int d = 0; d < 8; ++d) pz = fmaf(W0g[z * 8 + d], v0[d], pz);
          float r = (qn - pz) * rsz[z];
          part = fmaf(-0.5f * r, r, part);
        }
      } else {
        float pmv[16];
#pragma unroll
        for (int s = 0; s < 16; ++s) pmv[s] = sPM[s][kk];
#pragma unroll
        for (int zi = 0; zi < 2; ++zi) {
          int z = zg * 2 + zi;
          float mq = sKx[z];
#pragma unroll
          for (int s = 0; s < 16; ++s) mq = fmaf(sOMA1[z][s], pmv[s], mq);
          float qn = mq;
#pragma unroll
          for (int s = 0; s < 16; ++s) qn = fmaf(sL1[z][s], ep[s], qn);
          sQz0[z][kk] = qn;
          qnv[zi] = qn;
          float pz = sPM[z][kk];
          float r = (qn - pz) * sRSZ1[z];
          part = fmaf(-0.5f * r, r, part);
        }
      }
      qn32[kk * 20 + zg] = packbf(qnv[0], qnv[1]);
      sLLC[zg][kk] = part;
    }
    __syncthreads();

    // ===== phase E: observation ll quad via MFMA ===========================
    {
      const int xh = wid >> 3, wp = wid & 7, p0 = wp * 16;
      short8v bq = zero8;
      if (q < 2) bq = *(const short8v*)&sQnT[p0 + r16][q * 8];
      float ea = 0.0f;
#pragma unroll
      for (int xt2 = 0; xt2 < 4; ++xt2) {
        const int xt = xh * 4 + xt2;
        short8v ab = (q < 2) ? sBF[xt][q * 16 + r16] : zero8;
        float4v d = MFMA_BF16(ab, bq, zero4);
        float4v xr = *(const float4v*)&sXR[xt * 16 + q * 4];
        float4v rx = *(const float4v*)&sRX[xt * 16 + q * 4];
        float d0 = xr.x - d.x * rx.x; ea = fmaf(d0, d0, ea);
        float d1 = xr.y - d.y * rx.y; ea = fmaf(d1, d1, ea);
        float d2 = xr.z - d.z * rx.z; ea = fmaf(d2, d2, ea);
        float d3 = xr.w - d.w * rx.w; ea = fmaf(d3, d3, ea);
      }
      ea += __shfl_xor(ea, 16, 64);
      ea += __shfl_xor(ea, 32, 64);
      if (q == 0) sLLE[xh][p0 + r16] = ea;
    }
    __syncthreads();

    // ===== phase F: log weights + logsumexp + resample for t+1 (wave 0) ====
    if (wid == 0) {
      float cc = (t == 0) ? cc0 : cc1;
      float lw0 = 0, lw1 = 0;
#pragma unroll
      for (int half = 0; half < 2; ++half) {
        int j = 2 * lane + half;
        float v = -0.5f * (sLLE[0][j] + sLLE[1][j]) + cobs + cc
                + sLLC[0][j] + sLLC[1][j] + sLLC[2][j] + sLLC[3][j]
                + sLLC[4][j] + sLLC[5][j] + sLLC[6][j] + sLLC[7][j];
        if (half) lw1 = v; else lw0 = v;
      }
      float mx = fmaxf(lw0, lw1);
#pragma unroll
      for (int d = 32; d >= 1; d >>= 1) mx = fmaxf(mx, __shfl_xor(mx, d, 64));
      float ea = __expf(lw0 - mx), eb = __expf(lw1 - mx);
      float se = ea + eb;
#pragma unroll
      for (int d = 32; d >= 1; d >>= 1) se += __shfl_xor(se, d, 64);
      elbo += logf(se) + mx - 4.85203026f;  // log(128)

      unsigned kt0, kt1, k1a, k1b, k2a, k2b;
      tf2x32(0u, 42u, 0u, (unsigned)(t + 1), kt0, kt1);
      tf2x32(kt0, kt1, 0u, 0u, k1a, k1b);
      tf2x32(kt0, kt1, 0u, 1u, k2a, k2b);
      if (lane == 0) { sK2b[0] = k2a; sK2b[1] = k2b; }
      float run = ea + eb;
#pragma unroll
      for (int d = 1; d < 64; d <<= 1) {
        float v = __shfl_up(run, (unsigned)d, 64);
        if (lane >= d) run += v;
      }
      float tot = __shfl(run, 63, 64);
      float inv = 1.0f / tot;
      sCW[2 * lane]     = (run - eb) * inv;
      sCW[2 * lane + 1] = run * inv;
      unsigned o0, o1;
      tf2x32(k1a, k1b, 0u, (unsigned)b, o0, o1);
      unsigned bits = o0 ^ o1;
      float u0 = __uint_as_float((bits >> 9) | 0x3f800000u) - 1.0f;
#pragma unroll
      for (int half = 0; half < 2; ++half) {
        int j = 2 * lane + half;
        float p = (u0 + (float)j) * 0.0078125f;
        int lo = 0, hi = 128;
#pragma unroll
        for (int itr = 0; itr < 7; ++itr) {
          int mid = (lo + hi) >> 1;
          bool cnd = sCW[mid] < p;
          lo = cnd ? mid + 1 : lo;
          hi = cnd ? hi : mid;
        }
        sIDX[j] = (lo > 127) ? 127 : lo;
      }
    }
    __syncthreads();
  }

  if (tid == 0) out[b] = -elbo * (1.0f / 512.0f);
}

extern "C" void kernel_launch(void* const* d_in, const int* in_sizes, int n_in,
                              void* d_out, int out_size, void* d_ws, size_t ws_size,
                              hipStream_t stream) {
  const float* x     = (const float*)d_in[0];
  const float* u     = (const float*)d_in[1];
  const float* R_z   = (const float*)d_in[2];
  const float* R_z0  = (const float*)d_in[3];
  const float* R_x   = (const float*)d_in[4];
  const float* B_obs = (const float*)d_in[5];
  const float* Obias = (const float*)d_in[6];
  const float* m     = (const float*)d_in[7];
  const float* n     = (const float*)d_in[8];
  const float* Wu    = (const float*)d_in[9];
  const float* h     = (const float*)d_in[10];
  const float* W0    = (const float*)d_in[11];
  const float* b0    = (const float*)d_in[12];
  float* ws = (float*)d_ws;
  float* outp = (float*)d_out;

  precomp_kernel<<<dim3(1), dim3(256), 0, stream>>>(R_z, R_z0, R_x, B_obs, ws);
  pf_kernel<<<dim3(128), dim3(1024), 0, stream>>>(x, u, B_obs, Obias, m, n, Wu, h,
                                                  W0, b0, ws, outp);
}